// Round 1
// baseline (392.920 us; speedup 1.0000x reference)
//
#include <hip/hip_runtime.h>
#include <stdint.h>

// B=2, S=2048, D=1024, H=16, HD=64. fp32 in, fp32 out, bf16 MFMA internally.

typedef __attribute__((ext_vector_type(8))) short short8;
typedef __attribute__((ext_vector_type(4))) float floatx4;

#define S_LEN 2048
#define D_DIM 1024
#define NH 16
#define HD 64
#define MTOT 4096   // B*S

__device__ __forceinline__ short f2bf(float f) {
    uint32_t u = __builtin_bit_cast(uint32_t, f);
    uint32_t r = u + 0x7fffu + ((u >> 16) & 1u);   // RNE
    return (short)(r >> 16);
}

// ---------------- cast X: fp32 -> bf16 ----------------
__global__ __launch_bounds__(256) void castx_kernel(const float* __restrict__ X,
                                                    short* __restrict__ Xb) {
    int i = blockIdx.x * 256 + threadIdx.x;          // one float4 per thread
    const float4 v = *(const float4*)(X + (size_t)i * 4);
    short4 o;
    o.x = f2bf(v.x); o.y = f2bf(v.y); o.z = f2bf(v.z); o.w = f2bf(v.w);
    *(short4*)(Xb + (size_t)i * 4) = o;
}

// ---------------- transpose+cast W[k][n] -> WT[n][k] bf16 ----------------
__global__ __launch_bounds__(256) void tcast_kernel(const float* __restrict__ W,
                                                    short* __restrict__ WT) {
    __shared__ float tile[32][33];
    const int bx = blockIdx.x * 32;  // k base
    const int by = blockIdx.y * 32;  // n base
    const int tx = threadIdx.x, ty = threadIdx.y;    // 32 x 8
    for (int i = 0; i < 32; i += 8)
        tile[ty + i][tx] = W[(size_t)(bx + ty + i) * D_DIM + by + tx];
    __syncthreads();
    for (int i = 0; i < 32; i += 8)
        WT[(size_t)(by + ty + i) * D_DIM + bx + tx] = f2bf(tile[tx][ty + i]);
}

// ---------------- GEMM: C[m][n] = sum_k A[m][k] * BT[n][k] ----------------
// M=4096, N=1024, K=1024. 128x128 tile / block, 4 waves, 4x4 16x16x32 MFMA per wave.
// mode 0: write bf16 into [B,H,S,HD]   (Q, K)
// mode 1: write bf16 into [B,H,HD,S]   (V transposed)
// mode 2: write fp32 row-major + bias  (final output)
#define LDT 40   // padded LDS stride (bf16 elems): 80B = 20 banks -> 2-way (free)

__global__ __launch_bounds__(256) void gemm_kernel(const short* __restrict__ A,
                                                   const short* __restrict__ BT,
                                                   float* __restrict__ outF,
                                                   short* __restrict__ outB,
                                                   const float* __restrict__ bias,
                                                   const int mode) {
    __shared__ __align__(16) short As[128 * LDT];
    __shared__ __align__(16) short Bs[128 * LDT];
    const int tid  = threadIdx.x;
    const int wave = tid >> 6, lane = tid & 63;
    const int ln   = lane & 15, quad = lane >> 4;
    const int m0   = blockIdx.x * 128, n0 = blockIdx.y * 128;
    const int mw   = (wave & 1) * 64,  nw = (wave >> 1) * 64;

    floatx4 acc[4][4] = {};

    for (int k0 = 0; k0 < D_DIM; k0 += 32) {
        __syncthreads();
        // stage A tile: 128 rows x 32 bf16 = 512 x 16B chunks
        for (int c = tid; c < 512; c += 256) {
            const int row = c >> 2, seg = c & 3;
            *(uint4*)(As + row * LDT + seg * 8) =
                *(const uint4*)(A + (size_t)(m0 + row) * D_DIM + k0 + seg * 8);
        }
        for (int c = tid; c < 512; c += 256) {
            const int row = c >> 2, seg = c & 3;
            *(uint4*)(Bs + row * LDT + seg * 8) =
                *(const uint4*)(BT + (size_t)(n0 + row) * D_DIM + k0 + seg * 8);
        }
        __syncthreads();

        short8 a[4], b[4];
        for (int i = 0; i < 4; i++)
            a[i] = *(const short8*)(As + (mw + i * 16 + ln) * LDT + quad * 8);
        for (int j = 0; j < 4; j++)
            b[j] = *(const short8*)(Bs + (nw + j * 16 + ln) * LDT + quad * 8);
        for (int i = 0; i < 4; i++)
            for (int j = 0; j < 4; j++)
                acc[i][j] = __builtin_amdgcn_mfma_f32_16x16x32_bf16(a[i], b[j], acc[i][j], 0, 0, 0);
    }

    // epilogue: C/D layout col=lane&15, row=quad*4+reg  [m89-verified]
    for (int i = 0; i < 4; i++)
        for (int j = 0; j < 4; j++)
            for (int r = 0; r < 4; r++) {
                const int row = m0 + mw + i * 16 + quad * 4 + r;   // global m
                const int col = n0 + nw + j * 16 + ln;             // global n
                const float v = acc[i][j][r];
                if (mode == 2) {
                    outF[(size_t)row * D_DIM + col] = v + bias[col];
                } else {
                    const int bb = row >> 11, s = row & (S_LEN - 1);
                    const int h  = col >> 6,  hd = col & (HD - 1);
                    if (mode == 0)
                        outB[(((size_t)(bb * NH + h)) * S_LEN + s) * HD + hd] = f2bf(v);
                    else  // mode 1: V transposed [B,H,HD,S]
                        outB[(((size_t)(bb * NH + h)) * HD + hd) * S_LEN + s] = f2bf(v);
                }
            }
}

// ---------------- causal flash attention, unscaled scores ----------------
// grid: (S/64, B*H), 256 threads = 4 waves; wave w owns queries [q0+16w, q0+16w+16)
#define LKT 72   // padded stride: 144B = 36 banks ≡ 4 mod 32 -> 2-way (free)
#define L2E 1.44269504088896340736f

__global__ __launch_bounds__(256) void attn_kernel(const short* __restrict__ Q,
                                                   const short* __restrict__ Kg,
                                                   const short* __restrict__ Vt,
                                                   short* __restrict__ ctx) {
    __shared__ __align__(16) short Ks[64 * LKT];      // [key][hd]
    __shared__ __align__(16) short Vs[64 * LKT];      // [hd][key]  (V^T tile)
    __shared__ __align__(16) short Ps[4][16 * LKT];   // per-wave P [q][key]

    const int tid  = threadIdx.x;
    const int wave = tid >> 6, lane = tid & 63;
    const int ln   = lane & 15, quad = lane >> 4;
    const int qt   = blockIdx.x, bh = blockIdx.y;
    const int q0   = qt * 64;

    // Q fragments for this wave (constant across kv tiles): A-layout [m=ln][k=quad*8+j]
    const short* qrow = Q + ((size_t)bh * S_LEN + q0 + wave * 16 + ln) * HD;
    const short8 aq0 = *(const short8*)(qrow + quad * 8);
    const short8 aq1 = *(const short8*)(qrow + 32 + quad * 8);

    float m_run[4], l_run[4];
    floatx4 o_acc[4] = {};
    for (int r = 0; r < 4; r++) { m_run[r] = -INFINITY; l_run[r] = 0.f; }

    for (int kt = 0; kt <= qt; kt++) {
        const int k0 = kt * 64;
        __syncthreads();
        for (int c = tid; c < 512; c += 256) {       // K tile: [key][hd]
            const int row = c >> 3, seg = c & 7;
            *(uint4*)(Ks + row * LKT + seg * 8) =
                *(const uint4*)(Kg + ((size_t)bh * S_LEN + k0 + row) * HD + seg * 8);
        }
        for (int c = tid; c < 512; c += 256) {       // V^T tile: [hd][key]
            const int row = c >> 3, seg = c & 7;
            *(uint4*)(Vs + row * LKT + seg * 8) =
                *(const uint4*)(Vt + ((size_t)bh * HD + row) * S_LEN + k0 + seg * 8);
        }
        __syncthreads();

        // scores: S = Q @ K^T, 4 tiles of 16 keys
        floatx4 sc[4];
        for (int nt = 0; nt < 4; nt++) {
            const short8 b0 = *(const short8*)(Ks + (nt * 16 + ln) * LKT + quad * 8);
            const short8 b1 = *(const short8*)(Ks + (nt * 16 + ln) * LKT + 32 + quad * 8);
            floatx4 z = {};
            z = __builtin_amdgcn_mfma_f32_16x16x32_bf16(aq0, b0, z, 0, 0, 0);
            z = __builtin_amdgcn_mfma_f32_16x16x32_bf16(aq1, b1, z, 0, 0, 0);
            sc[nt] = z;
        }

        if (kt == qt) {  // diagonal tile: mask key > query
            for (int nt = 0; nt < 4; nt++)
                for (int r = 0; r < 4; r++) {
                    const int qrel = wave * 16 + quad * 4 + r;
                    const int krel = nt * 16 + ln;
                    if (krel > qrel) sc[nt][r] = -1e30f;
                }
        }

        // online softmax per query row (rows live in quad groups; reduce 16 lanes)
        float p[4][4], alpha[4];
        for (int r = 0; r < 4; r++) {
            float mt = fmaxf(fmaxf(sc[0][r], sc[1][r]), fmaxf(sc[2][r], sc[3][r]));
            for (int off = 1; off < 16; off <<= 1)
                mt = fmaxf(mt, __shfl_xor(mt, off, 64));
            const float mnew = fmaxf(m_run[r], mt);
            alpha[r] = exp2f((m_run[r] - mnew) * L2E);
            m_run[r] = mnew;
            float s = 0.f;
            for (int nt = 0; nt < 4; nt++) {
                const float e = exp2f((sc[nt][r] - mnew) * L2E);
                p[nt][r] = e;
                s += e;
            }
            for (int off = 1; off < 16; off <<= 1)
                s += __shfl_xor(s, off, 64);
            l_run[r] = l_run[r] * alpha[r] + s;
        }
        for (int dt = 0; dt < 4; dt++)
            for (int r = 0; r < 4; r++)
                o_acc[dt][r] *= alpha[r];

        // P -> LDS (wave-private) to convert C-layout -> A-layout
        for (int nt = 0; nt < 4; nt++)
            for (int r = 0; r < 4; r++)
                Ps[wave][(quad * 4 + r) * LKT + nt * 16 + ln] = f2bf(p[nt][r]);

        const short8 ap0 = *(const short8*)(&Ps[wave][ln * LKT + quad * 8]);
        const short8 ap1 = *(const short8*)(&Ps[wave][ln * LKT + 32 + quad * 8]);
        for (int dt = 0; dt < 4; dt++) {
            const short8 b0 = *(const short8*)(Vs + (dt * 16 + ln) * LKT + quad * 8);
            const short8 b1 = *(const short8*)(Vs + (dt * 16 + ln) * LKT + 32 + quad * 8);
            o_acc[dt] = __builtin_amdgcn_mfma_f32_16x16x32_bf16(ap0, b0, o_acc[dt], 0, 0, 0);
            o_acc[dt] = __builtin_amdgcn_mfma_f32_16x16x32_bf16(ap1, b1, o_acc[dt], 0, 0, 0);
        }
    }

    // epilogue: ctx[b][s][h*64+d] bf16
    const int bb = bh >> 4, h = bh & 15;
    for (int dt = 0; dt < 4; dt++)
        for (int r = 0; r < 4; r++) {
            const int s = q0 + wave * 16 + quad * 4 + r;
            const int d = dt * 16 + ln;
            const float v = o_acc[dt][r] / l_run[r];
            ctx[((size_t)(bb * S_LEN + s)) * D_DIM + h * HD + d] = f2bf(v);
        }
}

// ---------------- launch ----------------
extern "C" void kernel_launch(void* const* d_in, const int* in_sizes, int n_in,
                              void* d_out, int out_size, void* d_ws, size_t ws_size,
                              hipStream_t stream) {
    const float* X  = (const float*)d_in[0];
    const float* Wq = (const float*)d_in[1];
    const float* Wk = (const float*)d_in[2];
    const float* Wv = (const float*)d_in[3];
    const float* Wo = (const float*)d_in[4];
    const float* bo = (const float*)d_in[5];
    float* out = (float*)d_out;

    char* ws = (char*)d_ws;
    const size_t MB = 1024 * 1024;
    short* Xb   = (short*)(ws);                 // 8 MB  [4096][1024]
    short* WqT  = (short*)(ws + 8  * MB);       // 2 MB  [n][k]
    short* WkT  = (short*)(ws + 10 * MB);
    short* WvT  = (short*)(ws + 12 * MB);
    short* WoT  = (short*)(ws + 14 * MB);
    short* Qb   = (short*)(ws + 16 * MB);       // 8 MB  [B,H,S,HD]
    short* Kb   = (short*)(ws + 24 * MB);       // 8 MB  [B,H,S,HD]
    short* Vtb  = (short*)(ws + 32 * MB);       // 8 MB  [B,H,HD,S]
    short* ctxb = (short*)(ws + 40 * MB);       // 8 MB  [4096][1024]

    castx_kernel<<<4096, 256, 0, stream>>>(X, Xb);
    dim3 tg(32, 32), tb(32, 8);
    tcast_kernel<<<tg, tb, 0, stream>>>(Wq, WqT);
    tcast_kernel<<<tg, tb, 0, stream>>>(Wk, WkT);
    tcast_kernel<<<tg, tb, 0, stream>>>(Wv, WvT);
    tcast_kernel<<<tg, tb, 0, stream>>>(Wo, WoT);

    dim3 gg(32, 8);  // 4096/128 x 1024/128
    gemm_kernel<<<gg, 256, 0, stream>>>(Xb, WqT, nullptr, Qb,  nullptr, 0);
    gemm_kernel<<<gg, 256, 0, stream>>>(Xb, WkT, nullptr, Kb,  nullptr, 0);
    gemm_kernel<<<gg, 256, 0, stream>>>(Xb, WvT, nullptr, Vtb, nullptr, 1);

    dim3 ga(32, 32); // S/64 x B*H
    attn_kernel<<<ga, 256, 0, stream>>>(Qb, Kb, Vtb, ctxb);

    gemm_kernel<<<gg, 256, 0, stream>>>(ctxb, WoT, out, nullptr, bo, 2);
}

// Round 2
// 208.090 us; speedup vs baseline: 1.8882x; 1.8882x over previous
//
#include <hip/hip_runtime.h>
#include <stdint.h>

// B=2, S=2048, D=1024, H=16, HD=64. fp32 in/out, bf16 MFMA internally.

typedef __attribute__((ext_vector_type(8))) short short8;
typedef __attribute__((ext_vector_type(4))) float floatx4;

#define S_LEN 2048
#define D_DIM 1024
#define NH 16
#define HD 64
#define L2E 1.44269504088896340736f

__device__ __forceinline__ short f2bf(float f) {
    uint32_t u = __builtin_bit_cast(uint32_t, f);
    uint32_t r = u + 0x7fffu + ((u >> 16) & 1u);   // RNE
    return (short)(r >> 16);
}
__device__ __forceinline__ uint32_t pack2(float a, float b) {
    return (uint32_t)(uint16_t)f2bf(a) | ((uint32_t)(uint16_t)f2bf(b) << 16);
}
__device__ __forceinline__ void gll16(const void* g, void* l) {
    __builtin_amdgcn_global_load_lds(
        (const __attribute__((address_space(1))) void*)g,
        (__attribute__((address_space(3))) void*)l, 16, 0, 0);
}

// ---------------- cast X: fp32 -> bf16 ----------------
__global__ __launch_bounds__(256) void castx_kernel(const float* __restrict__ X,
                                                    short* __restrict__ Xb) {
    int i = blockIdx.x * 256 + threadIdx.x;
    const float4 v = *(const float4*)(X + (size_t)i * 4);
    short4 o;
    o.x = f2bf(v.x); o.y = f2bf(v.y); o.z = f2bf(v.z); o.w = f2bf(v.w);
    *(short4*)(Xb + (size_t)i * 4) = o;
}

// ---------------- transpose+cast W[k][n] -> WT[n][k] bf16 ----------------
__global__ __launch_bounds__(256) void tcast_kernel(const float* __restrict__ W,
                                                    short* __restrict__ WT) {
    __shared__ float tile[32][33];
    const int bx = blockIdx.x * 32;  // k base
    const int by = blockIdx.y * 32;  // n base
    const int tx = threadIdx.x, ty = threadIdx.y;    // 32 x 8
    for (int i = 0; i < 32; i += 8)
        tile[ty + i][tx] = W[(size_t)(bx + ty + i) * D_DIM + by + tx];
    __syncthreads();
    for (int i = 0; i < 32; i += 8)
        WT[(size_t)(by + ty + i) * D_DIM + bx + tx] = f2bf(tile[tx][ty + i]);
}

// ---------------- GEMM mainloop (m97 recipe) ----------------
// 128x128 tile, BK=64, unpadded LDS [row][64] bf16 with 16B-seg XOR swizzle
// (seg' = seg ^ (row&7)) so global_load_lds (wave-uniform dest) stays legal
// while b128 frag reads spread across banks.
__device__ __forceinline__ void gemm_main(const short* __restrict__ A,
                                          const short* __restrict__ BT,
                                          short* As, short* Bs,
                                          int m0, int n0, floatx4 (&acc)[4][4],
                                          int tid) {
    const int lane = tid & 63, ln = lane & 15, quad = lane >> 4;
    const int wave = tid >> 6;
    const int mw = (wave & 1) * 64, nw = (wave >> 1) * 64;
    for (int k0 = 0; k0 < D_DIM; k0 += 64) {
        __syncthreads();
        for (int t = 0; t < 4; t++) {
            const int c = t * 256 + tid;
            const int row = c >> 3, pos = c & 7, src = pos ^ (row & 7);
            gll16(A  + (size_t)(m0 + row) * D_DIM + k0 + src * 8, As + c * 8);
            gll16(BT + (size_t)(n0 + row) * D_DIM + k0 + src * 8, Bs + c * 8);
        }
        __syncthreads();
        for (int ks = 0; ks < 2; ks++) {
            short8 a[4], b[4];
            const int pos = ((ks * 4) ^ 0);  // seg base
            for (int i = 0; i < 4; i++) {
                const int row = mw + i * 16 + ln;
                a[i] = *(const short8*)(As + row * 64 + (((ks * 4 + quad) ^ (ln & 7)) * 8));
                (void)pos;
            }
            for (int j = 0; j < 4; j++) {
                const int row = nw + j * 16 + ln;
                b[j] = *(const short8*)(Bs + row * 64 + (((ks * 4 + quad) ^ (ln & 7)) * 8));
            }
            for (int i = 0; i < 4; i++)
                for (int j = 0; j < 4; j++)
                    acc[i][j] = __builtin_amdgcn_mfma_f32_16x16x32_bf16(a[i], b[j], acc[i][j], 0, 0, 0);
        }
    }
}

// fused QKV: BT = WqkvT [3*1024][1024]; grid (32, 24)
__global__ __launch_bounds__(256) void gemm_qkv_kernel(const short* __restrict__ Xb,
                                                       const short* __restrict__ WT,
                                                       short* __restrict__ Qb,
                                                       short* __restrict__ Kb,
                                                       short* __restrict__ Vtb) {
    __shared__ __align__(16) short As[128 * 64];
    __shared__ __align__(16) short Bs[128 * 64];
    const int m0 = blockIdx.x * 128, n0 = blockIdx.y * 128;
    floatx4 acc[4][4] = {};
    gemm_main(Xb, WT, As, Bs, m0, n0, acc, threadIdx.x);

    const int tid = threadIdx.x, wave = tid >> 6, lane = tid & 63;
    const int ln = lane & 15, quad = lane >> 4;
    const int mw = (wave & 1) * 64, nw = (wave >> 1) * 64;
    const int nsel = n0 >> 10;
    short* outB = (nsel == 0) ? Qb : (nsel == 1 ? Kb : Vtb);
    for (int i = 0; i < 4; i++)
        for (int j = 0; j < 4; j++)
            for (int r = 0; r < 4; r++) {
                const int row = m0 + mw + i * 16 + quad * 4 + r;   // token
                const int col = (n0 & 1023) + nw + j * 16 + ln;    // feature
                const int bb = row >> 11, s = row & (S_LEN - 1);
                const int h = col >> 6, hd = col & (HD - 1);
                const short v = f2bf(acc[i][j][r]);
                if (nsel < 2)
                    outB[(((size_t)(bb * NH + h)) * S_LEN + s) * HD + hd] = v;
                else
                    outB[(((size_t)(bb * NH + h)) * HD + hd) * S_LEN + s] = v;
            }
}

// output projection: C = ctx @ Wo + bo, fp32 out; grid (32, 8)
__global__ __launch_bounds__(256) void gemm_out_kernel(const short* __restrict__ Cb,
                                                       const short* __restrict__ WoT,
                                                       float* __restrict__ out,
                                                       const float* __restrict__ bias) {
    __shared__ __align__(16) short As[128 * 64];
    __shared__ __align__(16) short Bs[128 * 64];
    const int m0 = blockIdx.x * 128, n0 = blockIdx.y * 128;
    floatx4 acc[4][4] = {};
    gemm_main(Cb, WoT, As, Bs, m0, n0, acc, threadIdx.x);

    const int tid = threadIdx.x, wave = tid >> 6, lane = tid & 63;
    const int ln = lane & 15, quad = lane >> 4;
    const int mw = (wave & 1) * 64, nw = (wave >> 1) * 64;
    for (int i = 0; i < 4; i++)
        for (int j = 0; j < 4; j++)
            for (int r = 0; r < 4; r++) {
                const int row = m0 + mw + i * 16 + quad * 4 + r;
                const int col = n0 + nw + j * 16 + ln;
                out[(size_t)row * D_DIM + col] = acc[i][j][r] + bias[col];
            }
}

// ---------------- causal flash attention, S^T formulation ----------------
// Compute S^T = K·Q^T (queries on ln) so the key-reduction is in-lane + 2
// shuffles, alpha is per-lane-uniform, and P^T needs only a b64 LDS repack.
// Pairing: block (p, bh) does q-tiles p and 31-p => 33 kv-iters per block.
__global__ __launch_bounds__(256) void attn_kernel(const short* __restrict__ Q,
                                                   const short* __restrict__ Kg,
                                                   const short* __restrict__ Vt,
                                                   short* __restrict__ ctx) {
    __shared__ __align__(16) short Ks[64 * 64];       // [key][hd], xor-swizzled segs
    __shared__ __align__(16) short Vs[64 * 64];       // [hd][key], xor-swizzled segs
    __shared__ __align__(16) short Ps[4][16 * 72];    // per-wave [q][64] staging

    const int tid = threadIdx.x, wave = tid >> 6, lane = tid & 63;
    const int ln = lane & 15, quad = lane >> 4;
    const int bh = blockIdx.y, bb = bh >> 4, h = bh & 15;

    for (int half = 0; half < 2; half++) {
        const int qt = half ? (31 - blockIdx.x) : blockIdx.x;
        const int q0 = qt * 64;

        // Q as B-operand: B[n=ln (query)][k=quad*8+j (hd)]
        const short* qrow = Q + ((size_t)bh * S_LEN + q0 + wave * 16 + ln) * HD;
        const short8 qb0 = *(const short8*)(qrow + quad * 8);
        const short8 qb1 = *(const short8*)(qrow + 32 + quad * 8);

        float m_run = -INFINITY, l_run = 0.f;
        floatx4 o_acc[4] = {};

        for (int kt = 0; kt <= qt; kt++) {
            const int k0 = kt * 64;
            __syncthreads();
            for (int t = 0; t < 2; t++) {
                const int c = t * 256 + tid;
                const int row = c >> 3, pos = c & 7, src = pos ^ (row & 7);
                gll16(Kg + ((size_t)bh * S_LEN + k0 + row) * HD + src * 8, Ks + c * 8);
                gll16(Vt + ((size_t)bh * HD + row) * S_LEN + k0 + src * 8, Vs + c * 8);
            }
            __syncthreads();

            // S^T tiles: D[m=key (nt*16+quad*4+r)][n=query (ln)]
            floatx4 sc[4];
            for (int nt = 0; nt < 4; nt++) {
                const int row = nt * 16 + ln;
                const short8 ak0 = *(const short8*)(Ks + row * 64 + ((quad ^ (ln & 7)) * 8));
                const short8 ak1 = *(const short8*)(Ks + row * 64 + (((quad + 4) ^ (ln & 7)) * 8));
                floatx4 z = {};
                z = __builtin_amdgcn_mfma_f32_16x16x32_bf16(ak0, qb0, z, 0, 0, 0);
                z = __builtin_amdgcn_mfma_f32_16x16x32_bf16(ak1, qb1, z, 0, 0, 0);
                sc[nt] = z;
            }

            if (kt == qt) {  // mask key > query on the diagonal tile
                const int q_abs = q0 + wave * 16 + ln;
                for (int nt = 0; nt < 4; nt++)
                    for (int r = 0; r < 4; r++)
                        if (k0 + nt * 16 + quad * 4 + r > q_abs) sc[nt][r] = -1e30f;
            }

            // online softmax: query = ln; 16 in-lane values + 2 cross-quad shuffles
            float mt = sc[0][0];
            for (int nt = 0; nt < 4; nt++)
                for (int r = 0; r < 4; r++) mt = fmaxf(mt, sc[nt][r]);
            mt = fmaxf(mt, __shfl_xor(mt, 16, 64));
            mt = fmaxf(mt, __shfl_xor(mt, 32, 64));
            const float mnew = fmaxf(m_run, mt);
            const float alpha = exp2f((m_run - mnew) * L2E);
            float pv[4][4], ls = 0.f;
            for (int nt = 0; nt < 4; nt++)
                for (int r = 0; r < 4; r++) {
                    const float e = exp2f((sc[nt][r] - mnew) * L2E);
                    pv[nt][r] = e; ls += e;
                }
            ls += __shfl_xor(ls, 16, 64);
            ls += __shfl_xor(ls, 32, 64);
            l_run = l_run * alpha + ls;
            m_run = mnew;
            for (int dt = 0; dt < 4; dt++)
                for (int r = 0; r < 4; r++) o_acc[dt][r] *= alpha;

            // P^T -> B-operand layout via wave-private LDS [q=ln][key]
            for (int nt = 0; nt < 4; nt++) {
                uint2 u;
                u.x = pack2(pv[nt][0], pv[nt][1]);
                u.y = pack2(pv[nt][2], pv[nt][3]);
                *(uint2*)&Ps[wave][ln * 72 + nt * 16 + quad * 4] = u;
            }
            const short8 bp0 = *(const short8*)&Ps[wave][ln * 72 + quad * 8];
            const short8 bp1 = *(const short8*)&Ps[wave][ln * 72 + 32 + quad * 8];

            // O^T += V^T · P^T : D[m=d][n=q]
            for (int dt = 0; dt < 4; dt++) {
                const int row = dt * 16 + ln;
                const short8 av0 = *(const short8*)(Vs + row * 64 + ((quad ^ (ln & 7)) * 8));
                const short8 av1 = *(const short8*)(Vs + row * 64 + (((quad + 4) ^ (ln & 7)) * 8));
                o_acc[dt] = __builtin_amdgcn_mfma_f32_16x16x32_bf16(av0, bp0, o_acc[dt], 0, 0, 0);
                o_acc[dt] = __builtin_amdgcn_mfma_f32_16x16x32_bf16(av1, bp1, o_acc[dt], 0, 0, 0);
            }
        }

        // epilogue: transpose O^T through wave-private LDS -> coalesced stores
        const float rl = 1.f / l_run;
        for (int dt = 0; dt < 4; dt++) {
            uint2 u;
            u.x = pack2(o_acc[dt][0] * rl, o_acc[dt][1] * rl);
            u.y = pack2(o_acc[dt][2] * rl, o_acc[dt][3] * rl);
            *(uint2*)&Ps[wave][ln * 72 + dt * 16 + quad * 4] = u;   // [q=ln][d]
        }
        const int qr = lane >> 2, sg = lane & 3;
        for (int c = 0; c < 2; c++) {
            const short8 v = *(const short8*)&Ps[wave][qr * 72 + sg * 8 + c * 32];
            const int q = q0 + wave * 16 + qr;
            *(short8*)(ctx + ((size_t)bb * S_LEN + q) * D_DIM + h * HD + sg * 8 + c * 32) = v;
        }
    }
}

// ---------------- launch ----------------
extern "C" void kernel_launch(void* const* d_in, const int* in_sizes, int n_in,
                              void* d_out, int out_size, void* d_ws, size_t ws_size,
                              hipStream_t stream) {
    const float* X  = (const float*)d_in[0];
    const float* Wq = (const float*)d_in[1];
    const float* Wk = (const float*)d_in[2];
    const float* Wv = (const float*)d_in[3];
    const float* Wo = (const float*)d_in[4];
    const float* bo = (const float*)d_in[5];
    float* out = (float*)d_out;

    char* ws = (char*)d_ws;
    const size_t MB = 1024 * 1024;
    short* Xb     = (short*)(ws);                 // 8 MB  [4096][1024]
    short* WqkvT  = (short*)(ws + 8  * MB);       // 6 MB  [3*1024][1024]
    short* WoT    = (short*)(ws + 14 * MB);       // 2 MB
    short* Qb     = (short*)(ws + 16 * MB);       // 8 MB  [B,H,S,HD]
    short* Kb     = (short*)(ws + 24 * MB);       // 8 MB  [B,H,S,HD]
    short* Vtb    = (short*)(ws + 32 * MB);       // 8 MB  [B,H,HD,S]
    short* ctxb   = (short*)(ws + 40 * MB);       // 8 MB  [4096][1024]

    castx_kernel<<<4096, 256, 0, stream>>>(X, Xb);
    dim3 tg(32, 32), tb(32, 8);
    tcast_kernel<<<tg, tb, 0, stream>>>(Wq, WqkvT);
    tcast_kernel<<<tg, tb, 0, stream>>>(Wk, WqkvT + 1024 * 1024);
    tcast_kernel<<<tg, tb, 0, stream>>>(Wv, WqkvT + 2 * 1024 * 1024);
    tcast_kernel<<<tg, tb, 0, stream>>>(Wo, WoT);

    dim3 gq(32, 24);   // M=4096/128, N=3072/128
    gemm_qkv_kernel<<<gq, 256, 0, stream>>>(Xb, WqkvT, Qb, Kb, Vtb);

    dim3 ga(16, 32);   // 16 balanced q-tile pairs x B*H
    attn_kernel<<<ga, 256, 0, stream>>>(Qb, Kb, Vtb, ctxb);

    dim3 go(32, 8);
    gemm_out_kernel<<<go, 256, 0, stream>>>(ctxb, WoT, out, bo);
}

// Round 3
// 199.829 us; speedup vs baseline: 1.9663x; 1.0413x over previous
//
#include <hip/hip_runtime.h>
#include <stdint.h>

// B=2, S=2048, D=1024, H=16, HD=64. fp32 in/out, bf16 MFMA internally.

typedef __attribute__((ext_vector_type(8))) short short8;
typedef __attribute__((ext_vector_type(4))) float floatx4;

#define S_LEN 2048
#define D_DIM 1024
#define NH 16
#define HD 64
#define L2E 1.44269504088896340736f

__device__ __forceinline__ short f2bf(float f) {
    uint32_t u = __builtin_bit_cast(uint32_t, f);
    uint32_t r = u + 0x7fffu + ((u >> 16) & 1u);   // RNE
    return (short)(r >> 16);
}
__device__ __forceinline__ uint32_t pack2(float a, float b) {
#if __has_builtin(__builtin_amdgcn_cvt_pk_bf16_f32)
    auto v = __builtin_amdgcn_cvt_pk_bf16_f32(a, b);   // v_cvt_pk_bf16_f32 (gfx950)
    uint32_t r; __builtin_memcpy(&r, &v, sizeof(r)); return r;
#else
    return (uint32_t)(uint16_t)f2bf(a) | ((uint32_t)(uint16_t)f2bf(b) << 16);
#endif
}
__device__ __forceinline__ void gll16(const void* g, void* l) {
    __builtin_amdgcn_global_load_lds(
        (const __attribute__((address_space(1))) void*)g,
        (__attribute__((address_space(3))) void*)l, 16, 0, 0);
}

// ---------------- cast X: fp32 -> bf16 ----------------
__global__ __launch_bounds__(256) void castx_kernel(const float* __restrict__ X,
                                                    short* __restrict__ Xb) {
    int i = blockIdx.x * 256 + threadIdx.x;
    const float4 v = *(const float4*)(X + (size_t)i * 4);
    uint2 o;
    o.x = pack2(v.x, v.y);
    o.y = pack2(v.z, v.w);
    *(uint2*)(Xb + (size_t)i * 4) = o;
}

// ------------- transpose+cast all 4 weights in one launch -------------
__global__ __launch_bounds__(256) void tcast4_kernel(const float* __restrict__ Wq,
                                                     const float* __restrict__ Wk,
                                                     const float* __restrict__ Wv,
                                                     const float* __restrict__ Wo,
                                                     short* __restrict__ WqkvT,
                                                     short* __restrict__ WoT) {
    const int z = blockIdx.z;
    const float* W = (z == 0) ? Wq : (z == 1) ? Wk : (z == 2) ? Wv : Wo;
    short* WT = (z < 3) ? (WqkvT + (size_t)z * 1024 * 1024) : WoT;
    __shared__ float tile[32][33];
    const int bx = blockIdx.x * 32;  // k base
    const int by = blockIdx.y * 32;  // n base
    const int tx = threadIdx.x, ty = threadIdx.y;    // 32 x 8
    for (int i = 0; i < 32; i += 8)
        tile[ty + i][tx] = W[(size_t)(bx + ty + i) * D_DIM + by + tx];
    __syncthreads();
    for (int i = 0; i < 32; i += 8)
        WT[(size_t)(by + ty + i) * D_DIM + bx + tx] = f2bf(tile[tx][ty + i]);
}

// ---------------- GEMM mainloop (m97 recipe) ----------------
// 128x128 tile, BK=64, unpadded LDS [row][64] bf16 with 16B-seg XOR swizzle.
__device__ __forceinline__ void gemm_main(const short* __restrict__ A,
                                          const short* __restrict__ BT,
                                          short* As, short* Bs,
                                          int m0, int n0, floatx4 (&acc)[4][4],
                                          int tid) {
    const int lane = tid & 63, ln = lane & 15, quad = lane >> 4;
    const int wave = tid >> 6;
    const int mw = (wave & 1) * 64, nw = (wave >> 1) * 64;
    for (int k0 = 0; k0 < D_DIM; k0 += 64) {
        __syncthreads();
        for (int t = 0; t < 4; t++) {
            const int c = t * 256 + tid;
            const int row = c >> 3, pos = c & 7, src = pos ^ (row & 7);
            gll16(A  + (size_t)(m0 + row) * D_DIM + k0 + src * 8, As + c * 8);
            gll16(BT + (size_t)(n0 + row) * D_DIM + k0 + src * 8, Bs + c * 8);
        }
        __syncthreads();
        for (int ks = 0; ks < 2; ks++) {
            short8 a[4], b[4];
            for (int i = 0; i < 4; i++) {
                const int row = mw + i * 16 + ln;
                a[i] = *(const short8*)(As + row * 64 + (((ks * 4 + quad) ^ (ln & 7)) * 8));
            }
            for (int j = 0; j < 4; j++) {
                const int row = nw + j * 16 + ln;
                b[j] = *(const short8*)(Bs + row * 64 + (((ks * 4 + quad) ^ (ln & 7)) * 8));
            }
            for (int i = 0; i < 4; i++)
                for (int j = 0; j < 4; j++)
                    acc[i][j] = __builtin_amdgcn_mfma_f32_16x16x32_bf16(a[i], b[j], acc[i][j], 0, 0, 0);
        }
    }
}

// fused QKV: grid (32, 24)
__global__ __launch_bounds__(256) void gemm_qkv_kernel(const short* __restrict__ Xb,
                                                       const short* __restrict__ WT,
                                                       short* __restrict__ Qb,
                                                       short* __restrict__ Kb,
                                                       short* __restrict__ Vtb) {
    __shared__ __align__(16) short As[128 * 64];
    __shared__ __align__(16) short Bs[128 * 64];
    const int m0 = blockIdx.x * 128, n0 = blockIdx.y * 128;
    floatx4 acc[4][4] = {};
    gemm_main(Xb, WT, As, Bs, m0, n0, acc, threadIdx.x);

    const int tid = threadIdx.x, wave = tid >> 6, lane = tid & 63;
    const int ln = lane & 15, quad = lane >> 4;
    const int mw = (wave & 1) * 64, nw = (wave >> 1) * 64;
    const int nsel = n0 >> 10;
    short* outB = (nsel == 0) ? Qb : (nsel == 1 ? Kb : Vtb);
    for (int i = 0; i < 4; i++)
        for (int j = 0; j < 4; j++)
            for (int r = 0; r < 4; r++) {
                const int row = m0 + mw + i * 16 + quad * 4 + r;   // token
                const int col = (n0 & 1023) + nw + j * 16 + ln;    // feature
                const int bb = row >> 11, s = row & (S_LEN - 1);
                const int h = col >> 6, hd = col & (HD - 1);
                const short v = f2bf(acc[i][j][r]);
                if (nsel < 2)
                    outB[(((size_t)(bb * NH + h)) * S_LEN + s) * HD + hd] = v;
                else
                    outB[(((size_t)(bb * NH + h)) * HD + hd) * S_LEN + s] = v;
            }
}

// output projection: grid (32, 8)
__global__ __launch_bounds__(256) void gemm_out_kernel(const short* __restrict__ Cb,
                                                       const short* __restrict__ WoT,
                                                       float* __restrict__ out,
                                                       const float* __restrict__ bias) {
    __shared__ __align__(16) short As[128 * 64];
    __shared__ __align__(16) short Bs[128 * 64];
    const int m0 = blockIdx.x * 128, n0 = blockIdx.y * 128;
    floatx4 acc[4][4] = {};
    gemm_main(Cb, WoT, As, Bs, m0, n0, acc, threadIdx.x);

    const int tid = threadIdx.x, wave = tid >> 6, lane = tid & 63;
    const int ln = lane & 15, quad = lane >> 4;
    const int mw = (wave & 1) * 64, nw = (wave >> 1) * 64;
    for (int i = 0; i < 4; i++)
        for (int j = 0; j < 4; j++)
            for (int r = 0; r < 4; r++) {
                const int row = m0 + mw + i * 16 + quad * 4 + r;
                const int col = n0 + nw + j * 16 + ln;
                out[(size_t)row * D_DIM + col] = acc[i][j][r] + bias[col];
            }
}

// ---------------- causal flash attention, S^T formulation + KV-split ----------------
// 1536 blocks: qt<16 unsplit (writes ctx); qt>=16 split into 2 key chunks
// (writes fp32 partials O,m,l). Dispatch order ~LPT (long chunks first);
// id&7 == bh&7 gives each XCD a 4-head working set (2 MB K+V < 4 MB L2).
__global__ __launch_bounds__(256) void attn_kernel(const short* __restrict__ Q,
                                                   const short* __restrict__ Kg,
                                                   const short* __restrict__ Vt,
                                                   short* __restrict__ ctx,
                                                   float* __restrict__ Opart,
                                                   float* __restrict__ Mlpart) {
    __shared__ __align__(16) short Ks[64 * 64];       // [key][hd], xor-swizzled segs
    __shared__ __align__(16) short Vs[64 * 64];       // [hd][key], xor-swizzled segs
    __shared__ __align__(16) short Ps[4][16 * 72];    // per-wave staging

    const int tid = threadIdx.x, wave = tid >> 6, lane = tid & 63;
    const int ln = lane & 15, quad = lane >> 4;

    const int id = blockIdx.x;            // 0..1535
    const int xcd = id & 7;
    const int j = id >> 3;                // 0..191
    const int bh = xcd + 8 * (j & 3);     // head-XCD affinity
    const int t = j >> 2;                 // 0..47
    int qt, k_begin, k_end, pidx;
    if (t < 32) {                         // split tasks, qt = 31..16, LPT-ish
        qt = 31 - (t >> 1);
        const int half = t & 1;
        const int n = qt + 1, h0 = n >> 1;
        k_begin = half ? h0 : 0;
        k_end   = half ? n  : h0;
        pidx = ((qt - 16) * 32 + bh) * 2 + half;
    } else {                              // unsplit, qt = 15..0
        qt = 47 - t;
        k_begin = 0; k_end = qt + 1;
        pidx = -1;
    }
    const int q0 = qt * 64;
    const int bb = bh >> 4, h = bh & 15;

    // Q as B-operand: B[n=ln (query)][k=quad*8+j (hd)]
    const short* qrow = Q + ((size_t)bh * S_LEN + q0 + wave * 16 + ln) * HD;
    const short8 qb0 = *(const short8*)(qrow + quad * 8);
    const short8 qb1 = *(const short8*)(qrow + 32 + quad * 8);

    float m_run = -INFINITY, l_run = 0.f;
    floatx4 o_acc[4] = {};

    for (int kt = k_begin; kt < k_end; kt++) {
        const int k0 = kt * 64;
        __syncthreads();
        for (int tt = 0; tt < 2; tt++) {
            const int c = tt * 256 + tid;
            const int row = c >> 3, pos = c & 7, src = pos ^ (row & 7);
            gll16(Kg + ((size_t)bh * S_LEN + k0 + row) * HD + src * 8, Ks + c * 8);
            gll16(Vt + ((size_t)bh * HD + row) * S_LEN + k0 + src * 8, Vs + c * 8);
        }
        __syncthreads();

        // S^T tiles: D[m=key (nt*16+quad*4+r)][n=query (ln)]
        floatx4 sc[4];
        for (int nt = 0; nt < 4; nt++) {
            const int row = nt * 16 + ln;
            const short8 ak0 = *(const short8*)(Ks + row * 64 + ((quad ^ (ln & 7)) * 8));
            const short8 ak1 = *(const short8*)(Ks + row * 64 + (((quad + 4) ^ (ln & 7)) * 8));
            floatx4 z = {};
            z = __builtin_amdgcn_mfma_f32_16x16x32_bf16(ak0, qb0, z, 0, 0, 0);
            z = __builtin_amdgcn_mfma_f32_16x16x32_bf16(ak1, qb1, z, 0, 0, 0);
            sc[nt] = z;
        }

        if (kt == qt) {  // diagonal tile: mask key > query
            const int q_abs = q0 + wave * 16 + ln;
            for (int nt = 0; nt < 4; nt++)
                for (int r = 0; r < 4; r++)
                    if (k0 + nt * 16 + quad * 4 + r > q_abs) sc[nt][r] = -1e30f;
        }

        // online softmax: query = ln; 16 in-lane values + 2 cross-quad shuffles
        float mt = sc[0][0];
        for (int nt = 0; nt < 4; nt++)
            for (int r = 0; r < 4; r++) mt = fmaxf(mt, sc[nt][r]);
        mt = fmaxf(mt, __shfl_xor(mt, 16, 64));
        mt = fmaxf(mt, __shfl_xor(mt, 32, 64));
        const float mnew = fmaxf(m_run, mt);
        const float alpha = exp2f((m_run - mnew) * L2E);
        float pv[4][4], ls = 0.f;
        for (int nt = 0; nt < 4; nt++)
            for (int r = 0; r < 4; r++) {
                const float e = exp2f((sc[nt][r] - mnew) * L2E);
                pv[nt][r] = e; ls += e;
            }
        ls += __shfl_xor(ls, 16, 64);
        ls += __shfl_xor(ls, 32, 64);
        l_run = l_run * alpha + ls;
        m_run = mnew;
        for (int dt = 0; dt < 4; dt++)
            for (int r = 0; r < 4; r++) o_acc[dt][r] *= alpha;

        // P^T -> B-operand layout via wave-private LDS [q=ln][key]
        for (int nt = 0; nt < 4; nt++) {
            uint2 u;
            u.x = pack2(pv[nt][0], pv[nt][1]);
            u.y = pack2(pv[nt][2], pv[nt][3]);
            *(uint2*)&Ps[wave][ln * 72 + nt * 16 + quad * 4] = u;
        }
        const short8 bp0 = *(const short8*)&Ps[wave][ln * 72 + quad * 8];
        const short8 bp1 = *(const short8*)&Ps[wave][ln * 72 + 32 + quad * 8];

        // O^T += V^T · P^T : D[m=d][n=q]
        for (int dt = 0; dt < 4; dt++) {
            const int row = dt * 16 + ln;
            const short8 av0 = *(const short8*)(Vs + row * 64 + ((quad ^ (ln & 7)) * 8));
            const short8 av1 = *(const short8*)(Vs + row * 64 + (((quad + 4) ^ (ln & 7)) * 8));
            o_acc[dt] = __builtin_amdgcn_mfma_f32_16x16x32_bf16(av0, bp0, o_acc[dt], 0, 0, 0);
            o_acc[dt] = __builtin_amdgcn_mfma_f32_16x16x32_bf16(av1, bp1, o_acc[dt], 0, 0, 0);
        }
    }

    if (pidx >= 0) {
        // split chunk: write unnormalized fp32 partials. o_acc[dt] covers
        // d = dt*16 + quad*4 + (0..3) for query q = wave*16 + ln.
        float* Ob = Opart + (size_t)pidx * 4096 + (wave * 16 + ln) * 64;
        for (int dt = 0; dt < 4; dt++)
            *(float4*)(Ob + dt * 16 + quad * 4) = *(float4*)&o_acc[dt];
        if (quad == 0) {
            Mlpart[(size_t)pidx * 128 + wave * 16 + ln]      = m_run;
            Mlpart[(size_t)pidx * 128 + 64 + wave * 16 + ln] = l_run;
        }
    } else {
        // unsplit: normalize, transpose via LDS, coalesced bf16 stores
        const float rl = 1.f / l_run;
        for (int dt = 0; dt < 4; dt++) {
            uint2 u;
            u.x = pack2(o_acc[dt][0] * rl, o_acc[dt][1] * rl);
            u.y = pack2(o_acc[dt][2] * rl, o_acc[dt][3] * rl);
            *(uint2*)&Ps[wave][ln * 72 + dt * 16 + quad * 4] = u;   // [q=ln][d]
        }
        const int qr = lane >> 2, sg = lane & 3;
        for (int c = 0; c < 2; c++) {
            const short8 v = *(const short8*)&Ps[wave][qr * 72 + sg * 8 + c * 32];
            const int s = q0 + wave * 16 + qr;
            *(short8*)(ctx + ((size_t)bb * S_LEN + s) * D_DIM + h * HD + sg * 8 + c * 32) = v;
        }
    }
}

// ---------------- combine split partials -> ctx ----------------
__global__ __launch_bounds__(256) void combine_kernel(const float* __restrict__ Opart,
                                                      const float* __restrict__ Mlpart,
                                                      short* __restrict__ ctx) {
    const int tile = blockIdx.x;          // 0..511
    const int qt = 16 + (tile >> 5), bh = tile & 31;
    const int bb = bh >> 4, h = bh & 15;
    const int p0 = ((qt - 16) * 32 + bh) * 2;
    const float* O0 = Opart + (size_t)p0 * 4096;
    const float* O1 = O0 + 4096;
    const float* ml0 = Mlpart + (size_t)p0 * 128;
    const float* ml1 = ml0 + 128;
    for (int e = threadIdx.x; e < 1024; e += 256) {
        const int q = e >> 4, dseg = e & 15;
        const float m0 = ml0[q], l0 = ml0[64 + q];
        const float m1 = ml1[q], l1 = ml1[64 + q];
        const float m = fmaxf(m0, m1);
        const float a0 = exp2f((m0 - m) * L2E), a1 = exp2f((m1 - m) * L2E);
        const float rl = 1.f / (l0 * a0 + l1 * a1);
        const float4 x0 = *(const float4*)(O0 + q * 64 + dseg * 4);
        const float4 x1 = *(const float4*)(O1 + q * 64 + dseg * 4);
        uint2 u;
        u.x = pack2((x0.x * a0 + x1.x * a1) * rl, (x0.y * a0 + x1.y * a1) * rl);
        u.y = pack2((x0.z * a0 + x1.z * a1) * rl, (x0.w * a0 + x1.w * a1) * rl);
        const int s = qt * 64 + q;
        *(uint2*)(ctx + ((size_t)bb * S_LEN + s) * D_DIM + h * HD + dseg * 4) = u;
    }
}

// ---------------- launch ----------------
extern "C" void kernel_launch(void* const* d_in, const int* in_sizes, int n_in,
                              void* d_out, int out_size, void* d_ws, size_t ws_size,
                              hipStream_t stream) {
    const float* X  = (const float*)d_in[0];
    const float* Wq = (const float*)d_in[1];
    const float* Wk = (const float*)d_in[2];
    const float* Wv = (const float*)d_in[3];
    const float* Wo = (const float*)d_in[4];
    const float* bo = (const float*)d_in[5];
    float* out = (float*)d_out;

    char* ws = (char*)d_ws;
    const size_t MB = 1024 * 1024;
    short* Xb     = (short*)(ws);                 //  0- 8 MB [4096][1024] (dead after QKV GEMM)
    short* WqkvT  = (short*)(ws + 8  * MB);       //  8-14 MB (dead after QKV GEMM)
    short* Qb     = (short*)(ws + 16 * MB);       // 16-24 MB [B,H,S,HD]
    short* Kb     = (short*)(ws + 24 * MB);       // 24-32 MB [B,H,S,HD]
    short* Vtb    = (short*)(ws + 32 * MB);       // 32-40 MB [B,H,HD,S]
    short* ctxb   = (short*)(ws + 40 * MB);       // 40-48 MB [4096][1024]
    short* WoT    = (short*)(ws + 48 * MB);       // 48-50 MB (alive until out GEMM)
    float* Opart  = (float*)(ws);                 //  0-16 MB, reuses Xb+WqkvT region
    float* Mlpart = (float*)(ws + 50 * MB);       // 50-50.5 MB

    castx_kernel<<<4096, 256, 0, stream>>>(X, Xb);
    dim3 tg(32, 32, 4), tb(32, 8);
    tcast4_kernel<<<tg, tb, 0, stream>>>(Wq, Wk, Wv, Wo, WqkvT, WoT);

    dim3 gq(32, 24);   // M=4096/128, N=3072/128
    gemm_qkv_kernel<<<gq, 256, 0, stream>>>(Xb, WqkvT, Qb, Kb, Vtb);

    attn_kernel<<<1536, 256, 0, stream>>>(Qb, Kb, Vtb, ctxb, Opart, Mlpart);
    combine_kernel<<<512, 256, 0, stream>>>(Opart, Mlpart, ctxb);

    dim3 go(32, 8);
    gemm_out_kernel<<<go, 256, 0, stream>>>(ctxb, WoT, out, bo);
}